// Round 9
// baseline (1185.326 us; speedup 1.0000x reference)
//
#include <hip/hip_runtime.h>

// ---------------------------------------------------------------------------
// NeuralCA fused step, multi-launch, 4 waves/SIMD, 1 tile/iter:
//   512-thread blocks (8 waves), 2-row blocks, 448 blocks, 2 blocks/CU
//   (46.3 KB LDS), __launch_bounds__(512,4) -> VGPR cap 128/wave.
//   Per-wave register demand held ~85-90 (one 16-px tile per iteration,
//   quarter-N weight split) so the allocator keeps weights RESIDENT
//   (R8 lesson: demand near the cap -> arrays demoted to scratch, VGPR=52).
//   waves 0-3 (G1, quarter wq): h1 chans {16*(2wq+n)+c16} of tile j
//   waves 4-7 (G23, quarter g): G2 chans of tile j-1; wave (j-2)&3 does
//        G3 full-K + epilogue of tile j-2
//   h1/h2 via double-buffered 1-tile LDS mailboxes, lgkm-only barriers.
// ---------------------------------------------------------------------------

typedef __attribute__((ext_vector_type(8))) short short8;
typedef __attribute__((ext_vector_type(4))) float float4v;
typedef __attribute__((ext_vector_type(2))) float float2v;

#define MFMA16(a, b, c) __builtin_amdgcn_mfma_f32_16x16x32_bf16((a), (b), (c), 0, 0, 0)

__device__ __forceinline__ short f2bf(float f) {
  unsigned u = __builtin_bit_cast(unsigned, f);
  return (short)((u + 0x8000u) >> 16);     // round-half-up
}

__device__ __forceinline__ unsigned pk2bf(float a, float b) {
#if __has_builtin(__builtin_amdgcn_cvt_pk_bf16_f32)
  typedef __attribute__((ext_vector_type(2))) __bf16 bf2;
  bf2 r = __builtin_amdgcn_cvt_pk_bf16_f32(a, b);
  return __builtin_bit_cast(unsigned, r);
#else
  unsigned ua = __builtin_bit_cast(unsigned, a), ub = __builtin_bit_cast(unsigned, b);
  return ((ua + 0x8000u) >> 16) | (((ub + 0x8000u) >> 16) << 16);
#endif
}

__device__ __forceinline__ void async16(const void* g, void* l) {
  __builtin_amdgcn_global_load_lds((const __attribute__((address_space(1))) void*)g,
                                   (__attribute__((address_space(3))) void*)l,
                                   16, 0, 0);
}

// LDS-only barrier (no vmcnt drain - global stores fly free)
__device__ __forceinline__ void sync_lds() {
  asm volatile("s_waitcnt lgkmcnt(0)\n\ts_barrier" ::: "memory");
}

// ---- workspace layout (bytes) ----
#define WS_WE    0          // W_eff^T [128][168] bf16 (K pad 144->168, zeros)
#define WS_W2    43008      // W2^T    [128][136] bf16 (K sigma-permuted)
#define WS_W3    77824      // W3^T    [ 16][136] bf16 (sigma-perm, pad 2560)
#define WS_B1    82944      // b1 sigma-permuted f32 [128]
#define WS_B2    83456      // b2 sigma-permuted f32 [128]
#define WS_X32A  83968
#define WS_X32B  12929024
#define WS_X16A  25774080
#define WS_X16B  32196608

// ---------------------------------------------------------------------------
__global__ void prep_x(const float* __restrict__ x, float* __restrict__ x32,
                       short* __restrict__ x16) {
  int i = blockIdx.x * 256 + threadIdx.x;          // exactly 3211264 threads
  int w = i % 224;
  int h = (i / 224) % 224;
  int c = (i / 50176) & 15;
  int bb = i / 802816;
  float v = x[i];
  int o = ((bb * 224 + h) * 224 + w) * 16 + c;     // NHWC
  x32[o] = v;
  x16[o] = f2bf(v);
}

// sigma: stored position p holds channel chan(p) = 16*(p&7) + (p>>3)
__global__ void prep_w(const float* __restrict__ wp, const float* __restrict__ w1,
                       const float* __restrict__ b1, const float* __restrict__ w2,
                       const float* __restrict__ b2, const float* __restrict__ w3,
                       short* __restrict__ wE, short* __restrict__ w2t,
                       short* __restrict__ w3t, float* __restrict__ b1p,
                       float* __restrict__ b2p) {
  int i = blockIdx.x * 256 + threadIdx.x;          // exactly 41728 threads
  if (i < 21504) {                                  // W_eff^T [o=128][k=168]
    int o = i / 168, k = i % 168;
    float v = 0.f;
    if (k < 144) {
      int off = k >> 4, c = k & 15;                 // k = offset*16 + c
      for (int c3 = 0; c3 < 48; ++c3)
        v += w1[o * 48 + c3] * wp[c3 * 144 + c * 9 + off];
    }
    wE[i] = f2bf(v);
  } else if (i < 38912) {                           // W2^T perm [n=128][kk=136]
    int j = i - 21504;
    int n = j / 136, kk = j % 136;
    float v = 0.f;
    if (kk < 128) { int ch = 16 * (kk & 7) + (kk >> 3); v = w2[n * 128 + ch]; }
    w2t[j] = f2bf(v);
  } else if (i < 41472) {                           // W3^T perm, padded to 2560
    int j = i - 38912;
    float v = 0.f;
    if (j < 2176) {
      int n = j / 136, kk = j % 136;
      if (kk < 128) { int ch = 16 * (kk & 7) + (kk >> 3); v = w3[n * 128 + ch]; }
    }
    w3t[j] = f2bf(v);
  } else if (i < 41600) {
    int p = i - 41472;
    b1p[p] = b1[16 * (p & 7) + (p >> 3)];
  } else {
    int p = i - 41600;
    b2p[p] = b2[16 * (p & 7) + (p >> 3)];
  }
}

// ---------------------------------------------------------------------------
// One CA step. Block = 2 image rows, 512 threads = 8 waves. 28 tiles of
// 16 px; pipeline over 30 iterations, ONE tile per stage per iteration:
//   G1 wave wq:  iter j<28:     chan-quarter of h1, tile j      -> sBUF j&1
//   G23 wave g:  iter 1..28:    chan-quarter of h2, tile j-1    -> sH2  j&1
//   G23 wave (j-2)&3: iter>=2:  G3 full-K + epilogue, tile j-2 from sH2
template <bool LAST>
__global__ __launch_bounds__(512, 4) void ca_step(
    const short* __restrict__ wEg, const short* __restrict__ w2g,
    const short* __restrict__ w3g, const float* __restrict__ b1p,
    const float* __restrict__ b2p, const float* __restrict__ xs32,
    const short* __restrict__ xs16, float* __restrict__ xd32,
    short* __restrict__ xd16, float* __restrict__ dout) {
  __shared__ short sXH[4 * 3616];       // 28928 B  halo: 4 rows x 226 x 16ch
  __shared__ short sBUF[2 * 2176];      //  8704 B  h1 mailbox dbuf (1 tile)
  __shared__ short sH2[2 * 2176];       //  8704 B  h2 dbuf (1 tile)
  // total 46336 B -> 2 blocks/CU, 16 waves/CU = 4 waves/SIMD

  const int tid = threadIdx.x;
  const int lane = tid & 63;
  const int wv = tid >> 6;              // 0..7
  const int c16 = lane & 15;
  const int q = lane >> 4;
  const int q8 = q * 8;
  const int qh = q >> 1;
  const int c0 = (q & 1) * 8;

  const int blk = blockIdx.x;           // 448 = 4 batches x 112 rowgroups
  const int b = blk / 112;
  const int h0 = (blk % 112) * 2;

  // ---- stage halo: 4 rows x 7 chunks (1KB each); OOB rows -> zeros ----
  const short8 z8 = {0, 0, 0, 0, 0, 0, 0, 0};
  for (int t = wv; t < 28; t += 8) {
    int hr = t / 7, ck = t % 7;
    int hh = h0 - 1 + hr;
    char* l = (char*)sXH + hr * 7232 + 32 + ck * 1024;  // col 0 = image col -1
    if (hh >= 0 && hh < 224) {
      const char* g = (const char*)xs16 + ((size_t)(b * 224 + hh) * 224) * 32 + ck * 1024;
      async16(g + lane * 16, l);
    } else {
      *(short8*)(l + lane * 16) = z8;
    }
  }
  if (tid < 16) {   // zero edge columns (image col -1 and 224) for all 4 rows
    int hr = tid >> 2, wch = tid & 3;
    int colb = (wch < 2) ? 0 : 225;
    *(short8*)((char*)sXH + hr * 7232 + colb * 32 + (wch & 1) * 16) = z8;
  }

  if (wv < 4) {
    // ====== G1 role, chan-quarter wq: conv3x3+MLP1 fused =================
    const int wq = wv;
    short8 wf[5][2];                    // 40 VGPR
#pragma unroll
    for (int kc = 0; kc < 5; ++kc)
#pragma unroll
      for (int n = 0; n < 2; ++n)
        wf[kc][n] = *(const short8*)(wEg + ((2 * wq + n) * 16 + c16) * 168 + kc * 32 + q8);
    const float2v bH = *(const float2v*)(b1p + c16 * 8 + 2 * wq);

    __syncthreads();                    // halo ready (drains vmcnt)

    for (int j = 0; j < 30; ++j) {
      if (j < 28) {
        const int hb = ((j / 14) * 226 + (j % 14) * 16) * 16;
        float4v acc[2];
        acc[0] = (float4v){0.f, 0.f, 0.f, 0.f};
        acc[1] = (float4v){0.f, 0.f, 0.f, 0.f};
#pragma unroll
        for (int kc = 0; kc < 5; ++kc) {
          int off = kc * 2 + qh;
          if (off > 8) off = 8;         // K 144..159 hit zero rows of W_eff
          int dy = (off * 11) >> 5;     // off/3
          int dxx = off - dy * 3;
          short8 a = *(const short8*)(sXH + hb + (dy * 226 + dxx + c16) * 16 + c0);
          acc[0] = MFMA16(a, wf[kc][0], acc[0]);
          acc[1] = MFMA16(a, wf[kc][1], acc[1]);
        }
        short* dst = sBUF + (j & 1) * 2176;
#pragma unroll
        for (int r = 0; r < 4; ++r) {
          unsigned d = pk2bf(fmaxf(acc[0][r] + bH[0], 0.f),
                             fmaxf(acc[1][r] + bH[1], 0.f));
          *(unsigned*)(dst + (q * 4 + r) * 136 + c16 * 8 + 2 * wq) = d;
        }
      }
      sync_lds();
    }
  } else {
    // ====== G23 role, chan-quarter g: MLP2 quarter + rotating MLP3 =======
    const int g = wv - 4;
    short8 w2f[4][2];                   // 32 VGPR
    short8 w3f[4];                      // 16 VGPR
#pragma unroll
    for (int kc = 0; kc < 4; ++kc)
#pragma unroll
      for (int n = 0; n < 2; ++n)
        w2f[kc][n] = *(const short8*)(w2g + ((2 * g + n) * 16 + c16) * 136 + kc * 32 + q8);
#pragma unroll
    for (int kc = 0; kc < 4; ++kc)
      w3f[kc] = *(const short8*)(w3g + c16 * 136 + kc * 32 + q8);
    const float2v bG = *(const float2v*)(b2p + c16 * 8 + 2 * g);

    __syncthreads();                    // halo ready

    for (int j = 0; j < 30; ++j) {
      const bool own3 = (j >= 2) && (((j - 2) & 3) == g);
      float xres[4];
      int cb3 = 0, hglob3 = 0;
      if (own3) {                       // prefetch residual x for G3's tile
        const int t3 = j - 2;
        cb3 = (t3 % 14) * 16; hglob3 = h0 + t3 / 14;
#pragma unroll
        for (int r = 0; r < 4; ++r) {
          size_t pix = (size_t)(b * 224 + hglob3) * 224 + cb3 + q * 4 + r;
          xres[r] = xs32[pix * 16 + c16];
        }
      }
      if (j >= 1 && j <= 28) {          // G2 quarter on tile j-1
        const short* src = sBUF + ((j - 1) & 1) * 2176;
        float4v acc2[2];
        acc2[0] = (float4v){0.f, 0.f, 0.f, 0.f};
        acc2[1] = (float4v){0.f, 0.f, 0.f, 0.f};
#pragma unroll
        for (int kc = 0; kc < 4; ++kc) {
          short8 a = *(const short8*)(src + c16 * 136 + kc * 32 + q8);
          acc2[0] = MFMA16(a, w2f[kc][0], acc2[0]);
          acc2[1] = MFMA16(a, w2f[kc][1], acc2[1]);
        }
        short* dsth2 = sH2 + (j & 1) * 2176;
#pragma unroll
        for (int r = 0; r < 4; ++r) {
          unsigned d = pk2bf(fmaxf(acc2[0][r] + bG[0], 0.f),
                             fmaxf(acc2[1][r] + bG[1], 0.f));
          *(unsigned*)(dsth2 + (q * 4 + r) * 136 + c16 * 8 + 2 * g) = d;
        }
      }
      if (own3) {                       // G3 full-K + epilogue, tile j-2
        const short* srch2 = sH2 + ((j - 1) & 1) * 2176;
        float4v acc3 = (float4v){0.f, 0.f, 0.f, 0.f};
#pragma unroll
        for (int kc = 0; kc < 4; ++kc) {
          short8 a = *(const short8*)(srch2 + c16 * 136 + kc * 32 + q8);
          acc3 = MFMA16(a, w3f[kc], acc3);
        }
#pragma unroll
        for (int r = 0; r < 4; ++r) {
          int col = cb3 + q * 4 + r;
          size_t pix = (size_t)(b * 224 + hglob3) * 224 + col;
          float v = xres[r] + acc3[r];
          v = fminf(fmaxf(v, 0.f), 1.f);
          if (LAST) {
            dout[((size_t)(b * 16 + c16) * 224 + hglob3) * 224 + col] = v;  // NCHW
          } else {
            xd32[pix * 16 + c16] = v;
            xd16[pix * 16 + c16] = f2bf(v);
          }
        }
      }
      sync_lds();
    }
  }
}

// ---------------------------------------------------------------------------
extern "C" void kernel_launch(void* const* d_in, const int* in_sizes, int n_in,
                              void* d_out, int out_size, void* d_ws, size_t ws_size,
                              hipStream_t stream) {
  const float* x  = (const float*)d_in[0];
  const float* wp = (const float*)d_in[1];
  const float* w1 = (const float*)d_in[2];
  const float* b1 = (const float*)d_in[3];
  const float* w2 = (const float*)d_in[4];
  const float* b2 = (const float*)d_in[5];
  const float* w3 = (const float*)d_in[6];

  char* ws = (char*)d_ws;
  short* wEg = (short*)(ws + WS_WE);
  short* w2g = (short*)(ws + WS_W2);
  short* w3g = (short*)(ws + WS_W3);
  float* b1p = (float*)(ws + WS_B1);
  float* b2p = (float*)(ws + WS_B2);
  float* X32[2] = {(float*)(ws + WS_X32A), (float*)(ws + WS_X32B)};
  short* X16[2] = {(short*)(ws + WS_X16A), (short*)(ws + WS_X16B)};

  prep_x<<<12544, 256, 0, stream>>>(x, X32[0], X16[0]);
  prep_w<<<163, 256, 0, stream>>>(wp, w1, b1, w2, b2, w3, wEg, w2g, w3g, b1p, b2p);

  for (int s = 0; s < 39; ++s) {
    int sb = s & 1;
    ca_step<false><<<448, 512, 0, stream>>>(wEg, w2g, w3g, b1p, b2p,
                                            X32[sb], X16[sb],
                                            X32[1 - sb], X16[1 - sb], nullptr);
  }
  ca_step<true><<<448, 512, 0, stream>>>(wEg, w2g, w3g, b1p, b2p,
                                         X32[1], X16[1],
                                         X32[0], X16[0], (float*)d_out);
}

// Round 10
// 1019.872 us; speedup vs baseline: 1.1622x; 1.1622x over previous
//
#include <hip/hip_runtime.h>

// ---------------------------------------------------------------------------
// NeuralCA fused step, multi-launch, target 4 waves/SIMD with RESIDENT weights:
//   512-thread blocks (8 waves), 2-row blocks, 448 blocks, 2 blocks/CU
//   (68.9 KB LDS). __launch_bounds__(512,3): VGPR cap ~170 so the allocator
//   does NOT force-spill (R8: cap 128 < demand ~110+temps -> wholesale
//   demotion, VGPR=52, scratch churn). Natural demand is trimmed to ~90-105
//   (W3 evicted to LDS) so actual allocation should land <=128 -> 4 waves/SIMD.
//   waves 0-3 (G1, quarter wq): h1 chans {16*(2wq+n)+c16} of tiles {2j,2j+1}
//   waves 4-7 (G23, quarter g): G2 chans of tiles {2(j-1),2(j-1)+1};
//        waves g<2 also: G3 full-K (W3 from LDS) + epilogue of tile 2(j-2)+g
//   h1/h2 via double-buffered 2-tile LDS mailboxes, lgkm-only barriers.
// ---------------------------------------------------------------------------

typedef __attribute__((ext_vector_type(8))) short short8;
typedef __attribute__((ext_vector_type(4))) float float4v;
typedef __attribute__((ext_vector_type(2))) float float2v;

#define MFMA16(a, b, c) __builtin_amdgcn_mfma_f32_16x16x32_bf16((a), (b), (c), 0, 0, 0)

__device__ __forceinline__ short f2bf(float f) {
  unsigned u = __builtin_bit_cast(unsigned, f);
  return (short)((u + 0x8000u) >> 16);     // round-half-up
}

__device__ __forceinline__ unsigned pk2bf(float a, float b) {
#if __has_builtin(__builtin_amdgcn_cvt_pk_bf16_f32)
  typedef __attribute__((ext_vector_type(2))) __bf16 bf2;
  bf2 r = __builtin_amdgcn_cvt_pk_bf16_f32(a, b);
  return __builtin_bit_cast(unsigned, r);
#else
  unsigned ua = __builtin_bit_cast(unsigned, a), ub = __builtin_bit_cast(unsigned, b);
  return ((ua + 0x8000u) >> 16) | (((ub + 0x8000u) >> 16) << 16);
#endif
}

__device__ __forceinline__ void async16(const void* g, void* l) {
  // global -> LDS direct; LDS dest = wave-uniform base + lane*16
  __builtin_amdgcn_global_load_lds((const __attribute__((address_space(1))) void*)g,
                                   (__attribute__((address_space(3))) void*)l,
                                   16, 0, 0);
}

// LDS-only barrier (no vmcnt drain - global stores fly free)
__device__ __forceinline__ void sync_lds() {
  asm volatile("s_waitcnt lgkmcnt(0)\n\ts_barrier" ::: "memory");
}

// ---- workspace layout (bytes) ----
#define WS_WE    0          // W_eff^T [128][168] bf16 (K pad 144->168, zeros)
#define WS_W2    43008      // W2^T    [128][136] bf16 (K sigma-permuted)
#define WS_W3    77824      // W3^T    [ 16][136] bf16 (sigma-perm, pad 2560)
#define WS_B1    82944      // b1 sigma-permuted f32 [128]
#define WS_B2    83456      // b2 sigma-permuted f32 [128]
#define WS_X32A  83968
#define WS_X32B  12929024
#define WS_X16A  25774080
#define WS_X16B  32196608

// ---------------------------------------------------------------------------
__global__ void prep_x(const float* __restrict__ x, float* __restrict__ x32,
                       short* __restrict__ x16) {
  int i = blockIdx.x * 256 + threadIdx.x;          // exactly 3211264 threads
  int w = i % 224;
  int h = (i / 224) % 224;
  int c = (i / 50176) & 15;
  int bb = i / 802816;
  float v = x[i];
  int o = ((bb * 224 + h) * 224 + w) * 16 + c;     // NHWC
  x32[o] = v;
  x16[o] = f2bf(v);
}

// sigma: stored position p holds channel chan(p) = 16*(p&7) + (p>>3)
__global__ void prep_w(const float* __restrict__ wp, const float* __restrict__ w1,
                       const float* __restrict__ b1, const float* __restrict__ w2,
                       const float* __restrict__ b2, const float* __restrict__ w3,
                       short* __restrict__ wE, short* __restrict__ w2t,
                       short* __restrict__ w3t, float* __restrict__ b1p,
                       float* __restrict__ b2p) {
  int i = blockIdx.x * 256 + threadIdx.x;          // exactly 41728 threads
  if (i < 21504) {                                  // W_eff^T [o=128][k=168]
    int o = i / 168, k = i % 168;
    float v = 0.f;
    if (k < 144) {
      int off = k >> 4, c = k & 15;                 // k = offset*16 + c
      for (int c3 = 0; c3 < 48; ++c3)
        v += w1[o * 48 + c3] * wp[c3 * 144 + c * 9 + off];
    }
    wE[i] = f2bf(v);
  } else if (i < 38912) {                           // W2^T perm [n=128][kk=136]
    int j = i - 21504;
    int n = j / 136, kk = j % 136;
    float v = 0.f;
    if (kk < 128) { int ch = 16 * (kk & 7) + (kk >> 3); v = w2[n * 128 + ch]; }
    w2t[j] = f2bf(v);
  } else if (i < 41472) {                           // W3^T perm, padded to 2560
    int j = i - 38912;
    float v = 0.f;
    if (j < 2176) {
      int n = j / 136, kk = j % 136;
      if (kk < 128) { int ch = 16 * (kk & 7) + (kk >> 3); v = w3[n * 128 + ch]; }
    }
    w3t[j] = f2bf(v);
  } else if (i < 41600) {
    int p = i - 41472;
    b1p[p] = b1[16 * (p & 7) + (p >> 3)];
  } else {
    int p = i - 41600;
    b2p[p] = b2[16 * (p & 7) + (p >> 3)];
  }
}

// ---------------------------------------------------------------------------
// One CA step. Block = 2 image rows, 512 threads = 8 waves. 28 tiles of
// 16 px; pipeline over 16 iterations, two tiles per stage per iteration:
//   G1 wave wq:  iter j<14:     chan-quarter of h1, tiles {2j,2j+1} -> sBUF j&1
//   G23 wave g:  iter 1..14:    chan-quarter of h2, tiles {2(j-1),..} -> sH2 j&1
//   G23 g<2:     iter j>=2:     G3 full-K (W3 from LDS) + epilogue, tile 2(j-2)+g
template <bool LAST>
__global__ __launch_bounds__(512, 3) void ca_step(
    const short* __restrict__ wEg, const short* __restrict__ w2g,
    const short* __restrict__ w3g, const float* __restrict__ b1p,
    const float* __restrict__ b2p, const float* __restrict__ xs32,
    const short* __restrict__ xs16, float* __restrict__ xd32,
    short* __restrict__ xd16, float* __restrict__ dout) {
  __shared__ short sXH[4 * 3616];       // 28928 B  halo: 4 rows x 226 x 16ch
  __shared__ short sBUF[2 * 2 * 2176];  // 17408 B  h1 mailbox dbuf x 2 tiles
  __shared__ short sH2[2 * 2 * 2176];   // 17408 B  h2 dbuf x 2 tiles
  __shared__ short sW3[2560];           //  5120 B  W3^T (sigma-perm, padded)
  // total 68864 B -> 2 blocks/CU, 16 waves/CU = 4 waves/SIMD (if VGPR<=128)

  const int tid = threadIdx.x;
  const int lane = tid & 63;
  const int wv = tid >> 6;              // 0..7
  const int c16 = lane & 15;
  const int q = lane >> 4;
  const int q8 = q * 8;
  const int qh = q >> 1;
  const int c0 = (q & 1) * 8;

  const int blk = blockIdx.x;           // 448 = 4 batches x 112 rowgroups
  const int b = blk / 112;
  const int h0 = (blk % 112) * 2;

  // ---- stage halo: 4 rows x 7 chunks (1KB each); OOB rows -> zeros ----
  const short8 z8 = {0, 0, 0, 0, 0, 0, 0, 0};
  for (int t = wv; t < 28; t += 8) {
    int hr = t / 7, ck = t % 7;
    int hh = h0 - 1 + hr;
    char* l = (char*)sXH + hr * 7232 + 32 + ck * 1024;  // col 0 = image col -1
    if (hh >= 0 && hh < 224) {
      const char* g = (const char*)xs16 + ((size_t)(b * 224 + hh) * 224) * 32 + ck * 1024;
      async16(g + lane * 16, l);
    } else {
      *(short8*)(l + lane * 16) = z8;
    }
  }
  if (wv == 3) {    // stage W3^T into LDS: 5 chunks of 1KB
    for (int ck = 0; ck < 5; ++ck)
      async16((const char*)w3g + ck * 1024 + lane * 16, (char*)sW3 + ck * 1024);
  }
  if (tid < 16) {   // zero edge columns (image col -1 and 224) for all 4 rows
    int hr = tid >> 2, wch = tid & 3;
    int colb = (wch < 2) ? 0 : 225;
    *(short8*)((char*)sXH + hr * 7232 + colb * 32 + (wch & 1) * 16) = z8;
  }

  if (wv < 4) {
    // ====== G1 role, chan-quarter wq: conv3x3+MLP1 fused =================
    const int wq = wv;
    short8 wf[5][2];                    // 40 VGPR
#pragma unroll
    for (int kc = 0; kc < 5; ++kc)
#pragma unroll
      for (int n = 0; n < 2; ++n)
        wf[kc][n] = *(const short8*)(wEg + ((2 * wq + n) * 16 + c16) * 168 + kc * 32 + q8);
    const float2v bH = *(const float2v*)(b1p + c16 * 8 + 2 * wq);

    __syncthreads();                    // halo + sW3 ready (drains vmcnt)

    for (int j = 0; j < 16; ++j) {
      if (j < 14) {
        const int t0 = 2 * j, t1 = t0 + 1;
        const int hb0 = ((t0 / 14) * 226 + (t0 % 14) * 16) * 16;
        const int hb1 = ((t1 / 14) * 226 + (t1 % 14) * 16) * 16;
        float4v acc[2][2];
#pragma unroll
        for (int tt = 0; tt < 2; ++tt)
#pragma unroll
          for (int n = 0; n < 2; ++n) acc[tt][n] = (float4v){0.f, 0.f, 0.f, 0.f};
#pragma unroll
        for (int kc = 0; kc < 5; ++kc) {
          int off = kc * 2 + qh;
          if (off > 8) off = 8;         // K 144..159 hit zero rows of W_eff
          int dy = (off * 11) >> 5;     // off/3
          int dxx = off - dy * 3;
          const int ao = (dy * 226 + dxx + c16) * 16 + c0;
          short8 a0 = *(const short8*)(sXH + hb0 + ao);
          short8 a1 = *(const short8*)(sXH + hb1 + ao);
#pragma unroll
          for (int n = 0; n < 2; ++n) {
            acc[0][n] = MFMA16(a0, wf[kc][n], acc[0][n]);
            acc[1][n] = MFMA16(a1, wf[kc][n], acc[1][n]);
          }
        }
#pragma unroll
        for (int tt = 0; tt < 2; ++tt) {
          short* dst = sBUF + ((j & 1) * 2 + tt) * 2176;
#pragma unroll
          for (int r = 0; r < 4; ++r) {
            unsigned d = pk2bf(fmaxf(acc[tt][0][r] + bH[0], 0.f),
                               fmaxf(acc[tt][1][r] + bH[1], 0.f));
            *(unsigned*)(dst + (q * 4 + r) * 136 + c16 * 8 + 2 * wq) = d;
          }
        }
      }
      sync_lds();
    }
  } else {
    // ====== G23 role, chan-quarter g: MLP2 quarter + (g<2) MLP3/update ===
    const int g = wv - 4;
    short8 w2f[4][2];                   // 32 VGPR
#pragma unroll
    for (int kc = 0; kc < 4; ++kc)
#pragma unroll
      for (int n = 0; n < 2; ++n)
        w2f[kc][n] = *(const short8*)(w2g + ((2 * g + n) * 16 + c16) * 136 + kc * 32 + q8);
    const float2v bG = *(const float2v*)(b2p + c16 * 8 + 2 * g);

    __syncthreads();                    // halo + sW3 ready

    for (int j = 0; j < 16; ++j) {
      float xres[4];
      int cb3 = 0, hglob3 = 0;
      if (g < 2 && j >= 2) {            // prefetch residual x for G3's tile
        const int t3 = 2 * (j - 2) + g;
        cb3 = (t3 % 14) * 16; hglob3 = h0 + t3 / 14;
#pragma unroll
        for (int r = 0; r < 4; ++r) {
          size_t pix = (size_t)(b * 224 + hglob3) * 224 + cb3 + q * 4 + r;
          xres[r] = xs32[pix * 16 + c16];
        }
      }
      if (j >= 1 && j <= 14) {          // G2 quarter on tiles 2(j-1), 2(j-1)+1
        const short* srcA = sBUF + (((j - 1) & 1) * 2 + 0) * 2176;
        const short* srcB = sBUF + (((j - 1) & 1) * 2 + 1) * 2176;
        float4v acc2[2][2];
#pragma unroll
        for (int tt = 0; tt < 2; ++tt)
#pragma unroll
          for (int n = 0; n < 2; ++n) acc2[tt][n] = (float4v){0.f, 0.f, 0.f, 0.f};
#pragma unroll
        for (int kc = 0; kc < 4; ++kc) {
          short8 aA = *(const short8*)(srcA + c16 * 136 + kc * 32 + q8);
          short8 aB = *(const short8*)(srcB + c16 * 136 + kc * 32 + q8);
#pragma unroll
          for (int n = 0; n < 2; ++n) {
            acc2[0][n] = MFMA16(aA, w2f[kc][n], acc2[0][n]);
            acc2[1][n] = MFMA16(aB, w2f[kc][n], acc2[1][n]);
          }
        }
#pragma unroll
        for (int tt = 0; tt < 2; ++tt) {
          short* dsth2 = sH2 + ((j & 1) * 2 + tt) * 2176;
#pragma unroll
          for (int r = 0; r < 4; ++r) {
            unsigned d = pk2bf(fmaxf(acc2[tt][0][r] + bG[0], 0.f),
                               fmaxf(acc2[tt][1][r] + bG[1], 0.f));
            *(unsigned*)(dsth2 + (q * 4 + r) * 136 + c16 * 8 + 2 * g) = d;
          }
        }
      }
      if (g < 2 && j >= 2) {            // G3 full-K + epilogue, tile 2(j-2)+g
        const short* srch2 = sH2 + (((j - 1) & 1) * 2 + g) * 2176;
        float4v acc3 = (float4v){0.f, 0.f, 0.f, 0.f};
#pragma unroll
        for (int kc = 0; kc < 4; ++kc) {
          short8 a = *(const short8*)(srch2 + c16 * 136 + kc * 32 + q8);
          short8 w3f = *(const short8*)(sW3 + c16 * 136 + kc * 32 + q8);
          acc3 = MFMA16(a, w3f, acc3);
        }
#pragma unroll
        for (int r = 0; r < 4; ++r) {
          int col = cb3 + q * 4 + r;
          size_t pix = (size_t)(b * 224 + hglob3) * 224 + col;
          float v = xres[r] + acc3[r];
          v = fminf(fmaxf(v, 0.f), 1.f);
          if (LAST) {
            dout[((size_t)(b * 16 + c16) * 224 + hglob3) * 224 + col] = v;  // NCHW
          } else {
            xd32[pix * 16 + c16] = v;
            xd16[pix * 16 + c16] = f2bf(v);
          }
        }
      }
      sync_lds();
    }
  }
}

// ---------------------------------------------------------------------------
extern "C" void kernel_launch(void* const* d_in, const int* in_sizes, int n_in,
                              void* d_out, int out_size, void* d_ws, size_t ws_size,
                              hipStream_t stream) {
  const float* x  = (const float*)d_in[0];
  const float* wp = (const float*)d_in[1];
  const float* w1 = (const float*)d_in[2];
  const float* b1 = (const float*)d_in[3];
  const float* w2 = (const float*)d_in[4];
  const float* b2 = (const float*)d_in[5];
  const float* w3 = (const float*)d_in[6];

  char* ws = (char*)d_ws;
  short* wEg = (short*)(ws + WS_WE);
  short* w2g = (short*)(ws + WS_W2);
  short* w3g = (short*)(ws + WS_W3);
  float* b1p = (float*)(ws + WS_B1);
  float* b2p = (float*)(ws + WS_B2);
  float* X32[2] = {(float*)(ws + WS_X32A), (float*)(ws + WS_X32B)};
  short* X16[2] = {(short*)(ws + WS_X16A), (short*)(ws + WS_X16B)};

  prep_x<<<12544, 256, 0, stream>>>(x, X32[0], X16[0]);
  prep_w<<<163, 256, 0, stream>>>(wp, w1, b1, w2, b2, w3, wEg, w2g, w3g, b1p, b2p);

  for (int s = 0; s < 39; ++s) {
    int sb = s & 1;
    ca_step<false><<<448, 512, 0, stream>>>(wEg, w2g, w3g, b1p, b2p,
                                            X32[sb], X16[sb],
                                            X32[1 - sb], X16[1 - sb], nullptr);
  }
  ca_step<true><<<448, 512, 0, stream>>>(wEg, w2g, w3g, b1p, b2p,
                                         X32[1], X16[1],
                                         X32[0], X16[0], (float*)d_out);
}